// Round 6
// baseline (164.589 us; speedup 1.0000x reference)
//
#include <hip/hip_runtime.h>
#include <math.h>
#include <utility>

// Residual 4-level E8-root VQ — bit-exact argmin vs numpy reference
// (R1/R3/R4/R5 absmax 0.0). R6: TWO rows per thread for 2x per-wave ILP.
// R5 post-mortem: packed-asm slot count matched static count at ~1.6 GHz
// sustained (VALU-dense throttle), but VALUBusy fell to 74% — in-order issue
// bubbles on dependent cmp_eq->cndmask->fmin bookkeeping chains. Two
// independent row streams interleave to fill those bubbles; per-row
// instruction stream (and thus all roundings + tie-breaks) is IDENTICAL
// to the verified R5 chain.
// Numerics recap (verified): d2 = fmaf(-+2, dot, s), s = fl(res2+2);
// type-1 dots exact single adds; type-2 dots = sequential-k chain via
// MSB-first prefix tree + IEEE negation symmetry; reverse-order min3 scan
// with take-on-eq == first-index tie-break; chunk merge lower-wins-on-<=.

typedef float f2 __attribute__((ext_vector_type(2)));

constexpr int popc7(int v) {
  return ((v >> 0) & 1) + ((v >> 1) & 1) + ((v >> 2) & 1) + ((v >> 3) & 1) +
         ((v >> 4) & 1) + ((v >> 5) & 1) + ((v >> 6) & 1);
}
constexpr int pr_i(int p) {
  int c = 0;
  for (int i = 0; i < 8; ++i)
    for (int j = i + 1; j < 8; ++j) {
      if (c == p) return i;
      ++c;
    }
  return 0;
}
constexpr int pr_j(int p) {
  int c = 0;
  for (int i = 0; i < 8; ++i)
    for (int j = i + 1; j < 8; ++j) {
      if (c == p) return j;
      ++c;
    }
  return 0;
}

// (a,b) = (src0[S0] + src1[S1], src0[S0] - src1[S1])  — broadcast + neg_hi
template <int S0, int S1>
__device__ __forceinline__ f2 mk_ab(f2 a, f2 b) {
  f2 d;
  if constexpr (S0 == 0 && S1 == 0)
    asm("v_pk_add_f32 %0, %1, %2 op_sel:[0,0] op_sel_hi:[0,0] neg_hi:[0,1]" : "=v"(d) : "v"(a), "v"(b));
  else if constexpr (S0 == 0 && S1 == 1)
    asm("v_pk_add_f32 %0, %1, %2 op_sel:[0,1] op_sel_hi:[0,1] neg_hi:[0,1]" : "=v"(d) : "v"(a), "v"(b));
  else if constexpr (S0 == 1 && S1 == 0)
    asm("v_pk_add_f32 %0, %1, %2 op_sel:[1,0] op_sel_hi:[1,0] neg_hi:[0,1]" : "=v"(d) : "v"(a), "v"(b));
  else
    asm("v_pk_add_f32 %0, %1, %2 op_sel:[1,1] op_sel_hi:[1,1] neg_hi:[0,1]" : "=v"(d) : "v"(a), "v"(b));
  return d;
}

__device__ __forceinline__ f2 pkmul(f2 a, f2 b) {
  f2 d;
  asm("v_pk_mul_f32 %0, %1, %2" : "=v"(d) : "v"(a), "v"(b));
  return d;
}

// d2 pairs: ca = (-2, 2). Variants pick multiplier pair via op_sel on src0.
__device__ __forceinline__ f2 pkfma_mm(f2 ca, f2 v, f2 ss) {  // (-2,-2)
  f2 d;
  asm("v_pk_fma_f32 %0, %1, %2, %3 op_sel:[0,0,0] op_sel_hi:[0,1,1]" : "=v"(d) : "v"(ca), "v"(v), "v"(ss));
  return d;
}
__device__ __forceinline__ f2 pkfma_pp(f2 ca, f2 v, f2 ss) {  // (2,2)
  f2 d;
  asm("v_pk_fma_f32 %0, %1, %2, %3 op_sel:[1,0,0] op_sel_hi:[1,1,1]" : "=v"(d) : "v"(ca), "v"(v), "v"(ss));
  return d;
}
template <int P>  // P=0: (-2,2) as-is; P=1: (2,-2) swapped
__device__ __forceinline__ f2 pkfma_sw(f2 ca, f2 v, f2 ss) {
  f2 d;
  if constexpr (P == 0)
    asm("v_pk_fma_f32 %0, %1, %2, %3" : "=v"(d) : "v"(ca), "v"(v), "v"(ss));
  else
    asm("v_pk_fma_f32 %0, %1, %2, %3 op_sel:[1,0,0] op_sel_hi:[0,1,1]" : "=v"(d) : "v"(ca), "v"(v), "v"(ss));
  return d;
}

// tail step 1: src0 = EP (optionally swapped), src1 = h5 bcast (H2 hi).
template <bool SW, bool NEG>
__device__ __forceinline__ f2 tail1(f2 ep, f2 h2p) {
  f2 d;
  if constexpr (!SW && !NEG)
    asm("v_pk_add_f32 %0, %1, %2 op_sel:[0,1] op_sel_hi:[1,1] neg_hi:[0,1]" : "=v"(d) : "v"(ep), "v"(h2p));
  else if constexpr (!SW && NEG)
    asm("v_pk_add_f32 %0, %1, %2 op_sel:[0,1] op_sel_hi:[1,1] neg_lo:[0,1]" : "=v"(d) : "v"(ep), "v"(h2p));
  else if constexpr (SW && !NEG)
    asm("v_pk_add_f32 %0, %1, %2 op_sel:[1,1] op_sel_hi:[0,1] neg_hi:[0,1]" : "=v"(d) : "v"(ep), "v"(h2p));
  else
    asm("v_pk_add_f32 %0, %1, %2 op_sel:[1,1] op_sel_hi:[0,1] neg_lo:[0,1]" : "=v"(d) : "v"(ep), "v"(h2p));
  return d;
}
// tail steps 2/3: src0 = v (normal), src1 = H3 bcast lo (h6) or hi (h7).
template <int SEL, bool NEG>
__device__ __forceinline__ f2 tailn(f2 v, f2 h3p) {
  f2 d;
  if constexpr (SEL == 0 && !NEG)
    asm("v_pk_add_f32 %0, %1, %2 op_sel:[0,0] op_sel_hi:[1,0] neg_hi:[0,1]" : "=v"(d) : "v"(v), "v"(h3p));
  else if constexpr (SEL == 0 && NEG)
    asm("v_pk_add_f32 %0, %1, %2 op_sel:[0,0] op_sel_hi:[1,0] neg_lo:[0,1]" : "=v"(d) : "v"(v), "v"(h3p));
  else if constexpr (SEL == 1 && !NEG)
    asm("v_pk_add_f32 %0, %1, %2 op_sel:[0,1] op_sel_hi:[1,1] neg_hi:[0,1]" : "=v"(d) : "v"(v), "v"(h3p));
  else
    asm("v_pk_add_f32 %0, %1, %2 op_sel:[0,1] op_sel_hi:[1,1] neg_lo:[0,1]" : "=v"(d) : "v"(v), "v"(h3p));
  return d;
}

// one type-2 adjacent pair (candidates 112+T, 112+T+1), T even, reverse scan
template <int T>
__device__ __forceinline__ void t2pair(const f2 (&EP)[8], f2 h2p, f2 h3p,
                                       f2 ca, f2 ss, float& best, int& bi) {
  constexpr int p = popc7(T) & 1;
  constexpr int u = T ^ (p ? 127 : 0);  // lo-cand sign bits (0=+) for h1..h7
  constexpr int e = (((u >> 0) & 1) << 3) | (((u >> 1) & 1) << 2) |
                    (((u >> 2) & 1) << 1) | ((u >> 3) & 1);  // MSB-first
  constexpr bool sw = ((e >> 2) & 1) != 0;   // canon has bit2 == 0
  constexpr int canon = sw ? (e ^ 7) : e;
  constexpr int slot = (canon & 3) | ((canon >> 3) << 2);
  constexpr bool n5 = ((u >> 4) & 1) != 0;
  constexpr bool n6 = ((u >> 5) & 1) != 0;
  constexpr bool n7 = ((u >> 6) & 1) != 0;
  f2 v = tail1<sw, n5>(EP[slot], h2p);
  v = tailn<0, n6>(v, h3p);
  v = tailn<1, n7>(v, h3p);
  f2 d2 = pkfma_sw<p>(ca, v, ss);  // (fl(s-2*dot_lo), fl(s-2*dot_hi))
  const float nb = __builtin_fminf(__builtin_fminf(d2.x, d2.y), best);
  bi = (d2.y == nb) ? ((T & 63) + 1) : bi;  // higher index first
  bi = (d2.x == nb) ? (T & 63) : bi;        // lower index wins ties
  best = nb;
}

template <int BASE, int... K>
__device__ __forceinline__ void t2scan(std::integer_sequence<int, K...>,
                                       const f2 (&EP)[8], f2 h2p, f2 h3p,
                                       f2 ca, f2 ss, float& best, int& bi) {
  (t2pair<BASE - 2 * K>(EP, h2p, h3p, ca, ss, best, bi), ...);
}

// one type-1 (i,j) 4-group, reverse scan (ci+3, ci+2, ci+1, ci)
template <int PID>
__device__ __forceinline__ void t1pair(const f2 (&R)[4], f2 ca, f2 ss,
                                       float& best, int& bi) {
  constexpr int i = pr_i(PID), j = pr_j(PID);
  f2 ab = mk_ab<i & 1, j & 1>(R[i / 2], R[j / 2]);  // (ri+rj, ri-rj)
  f2 P = pkfma_mm(ca, ab, ss);  // (fl(s-2a)=d2_ci, fl(s-2b)=d2_ci+1)
  f2 Q = pkfma_pp(ca, ab, ss);  // (fl(s+2a)=d2_ci+3, fl(s+2b)=d2_ci+2)
  constexpr int l = 4 * PID - (PID >= 16 ? 64 : 0);  // chunk-local base
  const float nb = __builtin_fminf(__builtin_fminf(Q.x, Q.y), best);
  bi = (Q.x == nb) ? (l + 3) : bi;
  bi = (Q.y == nb) ? (l + 2) : bi;
  const float nb2 = __builtin_fminf(__builtin_fminf(P.x, P.y), nb);
  bi = (P.y == nb2) ? (l + 1) : bi;
  bi = (P.x == nb2) ? (l + 0) : bi;
  best = nb2;
}

template <int... K>
__device__ __forceinline__ void t1scanB(std::integer_sequence<int, K...>,
                                        const f2 (&R)[4], f2 ca, f2 ss,
                                        float& best, int& bi) {
  (t1pair<27 - K>(R, ca, ss, best, bi), ...);  // PID 27..16
}
template <int... K>
__device__ __forceinline__ void t1scanA(std::integer_sequence<int, K...>,
                                        const f2 (&R)[4], f2 ca, f2 ss,
                                        float& best, int& bi) {
  (t1pair<15 - K>(R, ca, ss, best, bi), ...);  // PID 15..0
}

// full 240-candidate argmin for one row's residual (verified R5 chain)
__device__ __forceinline__ int level_argmin(const f2 (&R)[4], f2 CA, f2 HF) {
#pragma clang fp contract(off)
  // res2, numpy pairwise order; s = fl(res2 + 2)
  const float q0 = R[0].x * R[0].x, q1 = R[0].y * R[0].y,
              q2 = R[1].x * R[1].x, q3 = R[1].y * R[1].y,
              q4 = R[2].x * R[2].x, q5 = R[2].y * R[2].y,
              q6 = R[3].x * R[3].x, q7 = R[3].y * R[3].y;
  const float res2 = ((q0 + q1) + (q2 + q3)) + ((q4 + q5) + (q6 + q7));
  const float s = res2 + 2.0f;
  f2 SS = {s, s};

  // halves and MSB-first prefix tree over h0..h4 (packed +- pairs)
  f2 H0 = pkmul(R[0], HF), H1 = pkmul(R[1], HF), H2 = pkmul(R[2], HF),
     H3 = pkmul(R[3], HF);
  f2 A = mk_ab<0, 1>(H0, H0);     // (h0+h1, h0-h1)
  f2 B01 = mk_ab<0, 0>(A, H1);    // (A0+h2, A0-h2)
  f2 B23 = mk_ab<1, 0>(A, H1);    // (A1+h2, A1-h2)
  f2 C01 = mk_ab<0, 1>(B01, H1);  // (B0+h3, B0-h3)
  f2 C23 = mk_ab<1, 1>(B01, H1);
  f2 C45 = mk_ab<0, 1>(B23, H1);
  f2 C67 = mk_ab<1, 1>(B23, H1);
  const float h4 = H2.x;
  // EP[slot] = (E[canon], E[canon^7]); E[e]=C[e>>1] + (e&1 ? -h4 : h4)
  f2 EP[8];
  EP[0].x = C01.x + h4; EP[0].y = C23.y - h4;  // (E0,  E7)
  EP[1].x = C01.x - h4; EP[1].y = C23.y + h4;  // (E1,  E6)
  EP[2].x = C01.y + h4; EP[2].y = C23.x - h4;  // (E2,  E5)
  EP[3].x = C01.y - h4; EP[3].y = C23.x + h4;  // (E3,  E4)
  EP[4].x = C45.x + h4; EP[4].y = C67.y - h4;  // (E8,  E15)
  EP[5].x = C45.x - h4; EP[5].y = C67.y + h4;  // (E9,  E14)
  EP[6].x = C45.y + h4; EP[6].y = C67.x - h4;  // (E10, E13)
  EP[7].x = C45.y - h4; EP[7].y = C67.x + h4;  // (E11, E12)

  const float FMAX = 3.4028235e38f;
  float bestA = FMAX, bestB = FMAX, bestC = FMAX, bestD = FMAX;
  int biA = 0, biB = 0, biC = 0, biD = 0;

  // reverse-order chunk scans
  t2scan<126>(std::make_integer_sequence<int, 32>{}, EP, H2, H3, CA, SS,
              bestD, biD);  // t = 126..64  (cands 176..239)
  t2scan<62>(std::make_integer_sequence<int, 32>{}, EP, H2, H3, CA, SS,
             bestC, biC);   // t = 62..0    (cands 112..175)
  t1scanB(std::make_integer_sequence<int, 12>{}, R, CA, SS, bestB, biB);
  t1scanA(std::make_integer_sequence<int, 16>{}, R, CA, SS, bestA, biA);

  // merge, lower chunk wins ties (<=)
  float best = bestD;
  int bi = biD + 176;
  { const bool k = bestC <= best; const int g = biC + 112;
    best = k ? bestC : best; bi = k ? g : bi; }
  { const bool k = bestB <= best; const int g = biB + 64;
    best = k ? bestB : best; bi = k ? g : bi; }
  { const bool k = bestA <= best;
    best = k ? bestA : best; bi = k ? biA : bi; }
  return bi;
}

__global__ __launch_bounds__(256) void e8_quant_kernel(
    const float* __restrict__ x, const float* __restrict__ roots,
    float* __restrict__ out, int nrow) {
#pragma clang fp contract(off)
  __shared__ float lroots[240 * 8];
  __shared__ float wred[4];
  for (int t = threadIdx.x; t < 240 * 8; t += 256) lroots[t] = roots[t];
  __syncthreads();

  const int row0 = blockIdx.x * 512 + threadIdx.x;  // row A
  const int row1 = row0 + 256;                      // row B
  const bool aA = row0 < nrow, aB = row1 < nrow;

  f2 XA[4] = {{0.f, 0.f}, {0.f, 0.f}, {0.f, 0.f}, {0.f, 0.f}};
  f2 XB[4] = {{0.f, 0.f}, {0.f, 0.f}, {0.f, 0.f}, {0.f, 0.f}};
  if (aA) {
    const float4 t0 = *(const float4*)(x + (size_t)row0 * 8);
    const float4 t1 = *(const float4*)(x + (size_t)row0 * 8 + 4);
    XA[0] = {t0.x, t0.y}; XA[1] = {t0.z, t0.w};
    XA[2] = {t1.x, t1.y}; XA[3] = {t1.z, t1.w};
  }
  if (aB) {
    const float4 t0 = *(const float4*)(x + (size_t)row1 * 8);
    const float4 t1 = *(const float4*)(x + (size_t)row1 * 8 + 4);
    XB[0] = {t0.x, t0.y}; XB[1] = {t0.z, t0.w};
    XB[2] = {t1.x, t1.y}; XB[3] = {t1.z, t1.w};
  }
  f2 QsA[4] = {{0.f, 0.f}, {0.f, 0.f}, {0.f, 0.f}, {0.f, 0.f}};
  f2 QsB[4] = {{0.f, 0.f}, {0.f, 0.f}, {0.f, 0.f}, {0.f, 0.f}};
  f2 RA[4], RB[4];
#pragma unroll
  for (int k = 0; k < 4; ++k) { RA[k] = XA[k]; RB[k] = XB[k]; }

  f2 CA = {-2.f, 2.f};
  f2 HF = {0.5f, 0.5f};
  float* out_idx = out + (size_t)nrow * 8;

#pragma unroll 1
  for (int lvl = 0; lvl < 4; ++lvl) {
    // two independent argmin streams — compiler interleaves for ILP
    const int biA = level_argmin(RA, CA, HF);
    const int biB = level_argmin(RB, CA, HF);

    if (aA) out_idx[(size_t)lvl * nrow + row0] = (float)biA;
    if (aB) out_idx[(size_t)lvl * nrow + row1] = (float)biB;

    // gather winning roots from LDS; update qsum and residual (ref order)
    const float4 raA = *(const float4*)(lroots + biA * 8);
    const float4 rbA = *(const float4*)(lroots + biA * 8 + 4);
    const float4 raB = *(const float4*)(lroots + biB * 8);
    const float4 rbB = *(const float4*)(lroots + biB * 8 + 4);
    QsA[0].x += raA.x; QsA[0].y += raA.y; QsA[1].x += raA.z; QsA[1].y += raA.w;
    QsA[2].x += rbA.x; QsA[2].y += rbA.y; QsA[3].x += rbA.z; QsA[3].y += rbA.w;
    QsB[0].x += raB.x; QsB[0].y += raB.y; QsB[1].x += raB.z; QsB[1].y += raB.w;
    QsB[2].x += rbB.x; QsB[2].y += rbB.y; QsB[3].x += rbB.z; QsB[3].y += rbB.w;
#pragma unroll
    for (int k = 0; k < 4; ++k) {
      RA[k].x = XA[k].x - QsA[k].x; RA[k].y = XA[k].y - QsA[k].y;
      RB[k].x = XB[k].x - QsB[k].x; RB[k].y = XB[k].y - QsB[k].y;
    }
  }

  // quantized_ste = (qsum + x) - x
  if (aA) {
    float o[8];
#pragma unroll
    for (int k = 0; k < 4; ++k) {
      o[2 * k] = (QsA[k].x + XA[k].x) - XA[k].x;
      o[2 * k + 1] = (QsA[k].y + XA[k].y) - XA[k].y;
    }
    *(float4*)(out + (size_t)row0 * 8) = make_float4(o[0], o[1], o[2], o[3]);
    *(float4*)(out + (size_t)row0 * 8 + 4) = make_float4(o[4], o[5], o[6], o[7]);
  }
  if (aB) {
    float o[8];
#pragma unroll
    for (int k = 0; k < 4; ++k) {
      o[2 * k] = (QsB[k].x + XB[k].x) - XB[k].x;
      o[2 * k + 1] = (QsB[k].y + XB[k].y) - XB[k].y;
    }
    *(float4*)(out + (size_t)row1 * 8) = make_float4(o[0], o[1], o[2], o[3]);
    *(float4*)(out + (size_t)row1 * 8 + 4) = make_float4(o[4], o[5], o[6], o[7]);
  }

  // qerr partials (mask inactive rows), block reduce, one atomic per block
  float eA = 0.f, eB = 0.f;
#pragma unroll
  for (int k = 0; k < 4; ++k) {
    eA = fmaf(RA[k].x, RA[k].x, eA); eA = fmaf(RA[k].y, RA[k].y, eA);
    eB = fmaf(RB[k].x, RB[k].x, eB); eB = fmaf(RB[k].y, RB[k].y, eB);
  }
  float e = (aA ? eA : 0.f) + (aB ? eB : 0.f);
#pragma unroll
  for (int off = 32; off > 0; off >>= 1) e += __shfl_down(e, off, 64);
  const int lane = threadIdx.x & 63, wv = threadIdx.x >> 6;
  if (lane == 0) wred[wv] = e;
  __syncthreads();
  if (threadIdx.x == 0) {
    const float scale = 1.0f / (float)((size_t)nrow * 8);  // 1/2^22, exact
    const float part = ((wred[0] + wred[1]) + (wred[2] + wred[3])) * scale;
    atomicAdd(out + (size_t)nrow * 12, part);
  }
}

extern "C" void kernel_launch(void* const* d_in, const int* in_sizes, int n_in,
                              void* d_out, int out_size, void* d_ws,
                              size_t ws_size, hipStream_t stream) {
  const float* x = (const float*)d_in[0];
  const float* roots = (const float*)d_in[1];
  float* out = (float*)d_out;

  const int nrow = in_sizes[0] / 8;
  const int nblocks = (nrow + 511) / 512;

  hipMemsetAsync(out + (size_t)nrow * 12, 0, sizeof(float), stream);
  e8_quant_kernel<<<nblocks, 256, 0, stream>>>(x, roots, out, nrow);
}